// Round 1
// baseline (276.314 us; speedup 1.0000x reference)
//
#include <hip/hip_runtime.h>
#include <cmath>

// ---------------- problem constants ----------------
#define NLAYERS 100      // hidden layers (scan)
#define DIN     64       // input features
#define WDIM    100      // hidden width
#define NTT     4        // 4 n-tiles of 32 (128 neuron cols; bias col = 100)
#define RT      2        // two 32-row tiles -> 64 rows per block
#define ROWS    64
#define KS      7        // 7 k-steps of 16 -> K=112 (useful 101)
#define PSTR    136      // f16 h row stride (272 B, b128-aligned)
#define BUF     (64 * PSTR)   // one 64-row h buffer in halves

typedef _Float16 half8  __attribute__((ext_vector_type(8)));
typedef _Float16 half2v __attribute__((ext_vector_type(2)));
typedef __fp16   fp16x2 __attribute__((ext_vector_type(2)));
typedef float    f32x4  __attribute__((ext_vector_type(4)));
typedef float    f32x16 __attribute__((ext_vector_type(16)));

// ---------------- workspace layout ----------------
// wsh: [l][ks7][nt4][lane][8] — frag stride 512 halves (1024 B).
// A-frag (32x32x16, operand-swapped W^T): lane -> neuron n = nt*32+(lane&31);
// elem j -> k = ks*16 + (lane>>5)*8 + j.
//   k<100 && n<100   -> Ws[l][k][n]
//   k==100 && n<100  -> bs[l][n]      (bias row vs h col 100 == 1.0)
//   k==100 && n==100 -> 1.0           (bias col self-sustains)
#define WSH_LAYER_HALVES (KS * NTT * 64 * 8)             // 14336
#define WSH_HALVES       (NLAYERS * WSH_LAYER_HALVES)    // 1,433,600
#define W0_HALVES        (4 * NTT * 64 * 8)              // 8192 (input, K=64 = 4 ks)
#define BPAD_FLOATS      128                             // b_in padded; col 100 = 1.0
#define OFF_BPAD_B       ((WSH_HALVES + W0_HALVES) * 2)
#define OFF_WOUT_B       (OFF_BPAD_B + BPAD_FLOATS * 4)
#define WOUT_FLOATS      128

// ============================================================
// prep v2: one block per (l,ks). Old prep read Ws with 400B-strided
// scalars (uncoalesced). Now: coalesced row reads -> 8KB LDS f32 tile
// [16k][128n] -> each thread emits one contiguous half8 frag slice
// (coalesced b128 stores). bid 700..703: input layer; bid 704: bpad+wout.
// ============================================================
__global__ __launch_bounds__(256)
void actor_prep(const float* __restrict__ Win, const float* __restrict__ bin,
                const float* __restrict__ Ws,  const float* __restrict__ bs,
                const float* __restrict__ Wout,
                _Float16* __restrict__ wsh, _Float16* __restrict__ w0sh,
                float* __restrict__ bpad, float* __restrict__ woutp) {
    __shared__ float tile[16 * 128];
    const int bid = blockIdx.x, tid = threadIdx.x;
    if (bid < NLAYERS * KS) {                       // hidden-layer weights
        const int l = bid / KS, ks = bid % KS;
#pragma unroll
        for (int e = 0; e < 8; ++e) {
            int idx = tid + 256 * e;                // coalesced: tid fastest
            int kk = idx >> 7, nn = idx & 127;
            int k = ks * 16 + kk;
            float v = 0.f;
            if (k < WDIM && nn < WDIM)        v = Ws[(l * WDIM + k) * WDIM + nn];
            else if (k == WDIM && nn < WDIM)  v = bs[l * WDIM + nn];   // bias row
            else if (k == WDIM && nn == WDIM) v = 1.0f;                // bias col alive
            tile[idx] = v;
        }
        __syncthreads();
        const int lane = tid & 63, nt = tid >> 6;
        const int g = lane >> 5, n = nt * 32 + (lane & 31);
        half8 o;
#pragma unroll
        for (int j = 0; j < 8; ++j) o[j] = (_Float16)tile[(g * 8 + j) * 128 + n];
        *(half8*)(wsh + (((l * KS + ks) * NTT + nt) << 9) + lane * 8) = o;
        return;
    }
    int b2 = bid - NLAYERS * KS;
    if (b2 < 4) {                                   // input layer (K=64)
        const int ks = b2;
#pragma unroll
        for (int e = 0; e < 8; ++e) {
            int idx = tid + 256 * e;
            int kk = idx >> 7, nn = idx & 127;
            int k = ks * 16 + kk;                   // < 64
            tile[idx] = (nn < WDIM) ? Win[k * WDIM + nn] : 0.f;
        }
        __syncthreads();
        const int lane = tid & 63, nt = tid >> 6;
        const int g = lane >> 5, n = nt * 32 + (lane & 31);
        half8 o;
#pragma unroll
        for (int j = 0; j < 8; ++j) o[j] = (_Float16)tile[(g * 8 + j) * 128 + n];
        *(half8*)(w0sh + ((ks * NTT + nt) << 9) + lane * 8) = o;
        return;
    }
    // last block: padded b_in (col 100 = 1.0 seed) + padded W_out
    if (tid < BPAD_FLOATS) {
        bpad[tid] = (tid < WDIM) ? bin[tid] : (tid == WDIM ? 1.0f : 0.f);
    } else {
        int t = tid - BPAD_FLOATS;
        if (t < WOUT_FLOATS) woutp[t] = (t < WDIM) ? Wout[t] : 0.f;
    }
}

// split fp32 -> hi/lo fp16 (layer-0 input only: keep input fidelity)
__device__ __forceinline__ void split8(const float* __restrict__ p, half8& hi, half8& lo) {
    f32x4 u0 = *(const f32x4*)p;
    f32x4 u1 = *(const f32x4*)(p + 4);
    float v[8] = {u0[0], u0[1], u0[2], u0[3], u1[0], u1[1], u1[2], u1[3]};
#pragma unroll
    for (int e = 0; e < 8; e += 2) {
        fp16x2 h = __builtin_amdgcn_cvt_pkrtz(v[e], v[e + 1]);
        float r0 = v[e]     - (float)h[0];
        float r1 = v[e + 1] - (float)h[1];
        fp16x2 l = __builtin_amdgcn_cvt_pkrtz(r0, r1);
        hi[e] = (_Float16)h[0]; hi[e + 1] = (_Float16)h[1];
        lo[e] = (_Float16)l[0]; lo[e + 1] = (_Float16)l[1];
    }
}

// epilogue one QUAD (regs 4qd..4qd+3 of a 32x32 C = 4 contiguous neurons):
// RNE f16 cvt, packed-f16 leaky, one b64 store
__device__ __forceinline__ void ep_quad(const f32x16 a, int qd, _Float16* __restrict__ d) {
    half2v p01, p23;
    p01[0] = (_Float16)a[4 * qd + 0]; p01[1] = (_Float16)a[4 * qd + 1];
    p23[0] = (_Float16)a[4 * qd + 2]; p23[1] = (_Float16)a[4 * qd + 3];
    const half2v slope = {(_Float16)0.01f, (_Float16)0.01f};
    p01 = __builtin_elementwise_max(p01, p01 * slope);
    p23 = __builtin_elementwise_max(p23, p23 * slope);
    uint2 w;
    w.x = __builtin_bit_cast(unsigned, p01);
    w.y = __builtin_bit_cast(unsigned, p23);
    *reinterpret_cast<uint2*>(d) = w;
}

// ============================================================
// Main r18: 256-thread blocks (4 waves), wave w owns ONE n-tile nt=w.
// vs r17 (2 waves, NTW=2, 255.8us):
//  (1) occupancy 8 -> 16 waves/CU (VGPR ~110 <= 128, LDS still 4 blk/CU):
//      2 waves/SIMD couldn't hide ds_read latency + MFMA dep chains —
//      ~60% of the 4600cy/layer wall was latency slack.
//  (2) h-LDS swizzle: half_off ^= ((row>>3)&1)<<5. PSTR=136 -> row
//      stride 68 words == 4 mod 32 -> rows {r,r+8,r+16,r+24} were a
//      4-way bank conflict (1.58x, m136) on EVERY h read/write —
//      matches measured SQ_LDS_BANK_CONFLICT (517cy/layer/CU). Swizzle
//      leaves only r/r+16 2-way (free). Applied to BOTH epi writes and
//      bh reads (both-sides-or-neither). 64B-granule XOR keeps 16B
//      alignment; no carries (base bits0-4 = 4g, +8*qd < 32).
//  (3) barrier = "s_waitcnt lgkmcnt(0); s_barrier": W-refill globals
//      are VGPR-private, don't drain vmcnt at the barrier (T4);
//      compiler inserts counted vmcnt before next-layer wb use.
// C/D layout (HW-verified m74/m101): col(batch)=lane&31,
// row(neuron)=(reg&3)+8*(reg>>2)+4*(lane>>5). h double-buffered by
// layer parity. HI-ONLY f16 activations (absmax 0.094, r8-r16).
// ============================================================
__global__ __launch_bounds__(256, 4)
void actor_main(const float* __restrict__ x,
                const _Float16* __restrict__ wsh,
                const _Float16* __restrict__ w0sh,
                const float* __restrict__ bpad,
                const float* __restrict__ woutp,
                const float* __restrict__ bout,
                float* __restrict__ out) {
    __shared__ __align__(16) _Float16 hp[2 * BUF];   // two 64-row h buffers
    const int lane = threadIdx.x & 63;
    const int wid  = threadIdx.x >> 6;   // 0..3: owns nt = wid
    const int g = lane >> 5, b31 = lane & 31;
    const int sw = ((b31 >> 3) & 1) << 5;            // bank swizzle (halves)
    const int rowbase = blockIdx.x * ROWS;

    f32x16 acc[RT];
    half8 wb[KS];                        // my W frags for the whole layer
    const f32x16 zero16 = {0,0,0,0, 0,0,0,0, 0,0,0,0, 0,0,0,0};

    // ---- input layer (K=64 = 4 k-steps of 16) ----
    {
        half8 w0[4];
#pragma unroll
        for (int ks = 0; ks < 4; ++ks)
            w0[ks] = *(const half8*)(w0sh + (ks * NTT + wid) * 512 + lane * 8);
#pragma unroll
        for (int rt = 0; rt < RT; ++rt)
#pragma unroll
            for (int qd = 0; qd < 4; ++qd) {
                f32x4 tq = *(const f32x4*)(bpad + wid * 32 + 8 * qd + 4 * g);
#pragma unroll
                for (int r = 0; r < 4; ++r) acc[rt][4 * qd + r] = tq[r];
            }
#pragma unroll
        for (int rt = 0; rt < RT; ++rt) {
            const float* xr = x + (rowbase + rt * 32 + b31) * DIN;
#pragma unroll
            for (int ks = 0; ks < 4; ++ks) {
                half8 xhi, xlo;
                split8(xr + ks * 16 + g * 8, xhi, xlo);
                acc[rt] = __builtin_amdgcn_mfma_f32_32x32x16_f16(w0[ks], xhi, acc[rt], 0, 0, 0);
                acc[rt] = __builtin_amdgcn_mfma_f32_32x32x16_f16(w0[ks], xlo, acc[rt], 0, 0, 0);
            }
        }
    }
    // epi0 -> buffer 0 (swizzled); prefetch W(0)
#pragma unroll
    for (int rt = 0; rt < RT; ++rt) {
        _Float16* d = hp + (rt * 32 + b31) * PSTR + ((wid * 32 + 4 * g) ^ sw);
#pragma unroll
        for (int qd = 0; qd < 4; ++qd) ep_quad(acc[rt], qd, d + 8 * qd);
    }
#pragma unroll
    for (int ks = 0; ks < KS; ++ks)
        wb[ks] = *(const half8*)(wsh + (ks * NTT + wid) * 512 + lane * 8);
    asm volatile("s_waitcnt lgkmcnt(0)\n\ts_barrier" ::: "memory");

    // ---------------- 100 hidden layers ----------------
    // layer l: reads buf[l&1] (h of l-1), writes buf[(l+1)&1]
#pragma unroll 1
    for (int l = 0; l < NLAYERS; ++l) {
        const _Float16* rb = hp + (l & 1) * BUF;
        _Float16* wbf = hp + ((l + 1) & 1) * BUF;
        const _Float16* wn = wsh + (l < NLAYERS - 1 ? l + 1 : l) * WSH_LAYER_HALVES;
        half8 bh[KS];

        // ---- chunk rt=0: 7-MFMA chain (4 waves/SIMD provide 4 chains) ----
#pragma unroll
        for (int ks = 0; ks < KS; ++ks)
            bh[ks] = *(const half8*)(rb + b31 * PSTR + ((ks * 16 + g * 8) ^ sw));
#pragma unroll
        for (int ks = 0; ks < KS; ++ks)
            acc[0] = __builtin_amdgcn_mfma_f32_32x32x16_f16(
                wb[ks], bh[ks], (ks == 0 ? zero16 : acc[0]), 0, 0, 0);

        // ---- chunk rt=1: chain || epi(rt0) || W(L+1) refill ----
#pragma unroll
        for (int ks = 0; ks < KS; ++ks)      // hoisted before epi writes
            bh[ks] = *(const half8*)(rb + (32 + b31) * PSTR + ((ks * 16 + g * 8) ^ sw));
        _Float16* d0 = wbf + b31 * PSTR + ((wid * 32 + 4 * g) ^ sw);
#pragma unroll
        for (int ks = 0; ks < KS; ++ks) {
            acc[1] = __builtin_amdgcn_mfma_f32_32x32x16_f16(
                wb[ks], bh[ks], (ks == 0 ? zero16 : acc[1]), 0, 0, 0);
            // wb[ks] dead after its rt1 mfma: refill with W(L+1)[ks]
            wb[ks] = *(const half8*)(wn + (ks * NTT + wid) * 512 + lane * 8);
            if (ks < 4)                      // epi of rt0 (this layer): 4 quads
                ep_quad(acc[0], ks, d0 + 8 * ks);
        }
        // tail: epi of rt1 (4 quads), then lgkm-only layer barrier
        {
            _Float16* d1 = wbf + (32 + b31) * PSTR + ((wid * 32 + 4 * g) ^ sw);
#pragma unroll
            for (int qd = 0; qd < 4; ++qd) ep_quad(acc[1], qd, d1 + 8 * qd);
        }
        asm volatile("s_waitcnt lgkmcnt(0)\n\ts_barrier" ::: "memory");
    }
    // acc[rt] = pre-activation of layer 99 for my nt (in regs)

    // ---------------- heads: leaky + dot(W_out), combine via LDS ----------------
    float part[RT];
#pragma unroll
    for (int rt = 0; rt < RT; ++rt) {
        float s = 0.f;
#pragma unroll
        for (int qd = 0; qd < 4; ++qd) {
            f32x4 w4 = *(const f32x4*)(woutp + wid * 32 + 8 * qd + 4 * g);
#pragma unroll
            for (int r = 0; r < 4; ++r) {
                float a = acc[rt][4 * qd + r];
                float v = fmaxf(a, 0.01f * a);
                s += v * w4[r];
            }
        }
        s += __shfl_xor(s, 32);              // combine the two k-groups
        part[rt] = s;
    }
    float* red = (float*)hp;                 // scratch (final barrier passed)
    if (lane < 32) {
        red[wid * 64 + b31]      = part[0];
        red[wid * 64 + 32 + b31] = part[1];
    }
    __syncthreads();
    {
        const int r = threadIdx.x;
        if (r < 64) {
            float tot = red[r] + red[64 + r] + red[128 + r] + red[192 + r] + bout[0];
            out[rowbase + r] = tanhf(tot) * 4.5f + 5.5f;   // (tanh+1)/2*9 + 1
        }
    }
}

extern "C" void kernel_launch(void* const* d_in, const int* in_sizes, int n_in,
                              void* d_out, int out_size, void* d_ws, size_t ws_size,
                              hipStream_t stream) {
    const float* x    = (const float*)d_in[0];
    const float* Win  = (const float*)d_in[1];
    const float* bin  = (const float*)d_in[2];
    const float* Ws   = (const float*)d_in[3];
    const float* bs   = (const float*)d_in[4];
    const float* Wout = (const float*)d_in[5];
    const float* bout = (const float*)d_in[6];
    float* out = (float*)d_out;

    char* ws = (char*)d_ws;
    _Float16* wsh  = (_Float16*)ws;
    _Float16* w0sh = wsh + WSH_HALVES;
    float* bpad  = (float*)(ws + OFF_BPAD_B);
    float* woutp = (float*)(ws + OFF_WOUT_B);

    hipLaunchKernelGGL(actor_prep, dim3(NLAYERS * KS + 4 + 1), dim3(256), 0, stream,
                       Win, bin, Ws, bs, Wout, wsh, w0sh, bpad, woutp);

    const int nrows = in_sizes[0] / DIN;   // 65536
    hipLaunchKernelGGL(actor_main, dim3(nrows / ROWS), dim3(256), 0, stream,
                       x, wsh, w0sh, bpad, woutp, bout, out);
}